// Round 1
// baseline (763.956 us; speedup 1.0000x reference)
//
#include <hip/hip_runtime.h>
#include <math.h>

#define PI_D 3.14159265358979323846

// ---------------- persistent device buffers (no d_ws dependence) -----------
__device__ double2 g_M05[128*128];
__device__ float2  g_Mf [128*128];
__device__ float2  g_Mb [128*128];
__device__ float2  g_F  [128*128];
__device__ float2  g_IF [128*128];
__device__ float   g_x1 [4*48*16384];
__device__ float2  g_bufA[64*16384];
__device__ float2  g_bufB[64*16384];
__device__ float   g_mag[64*16384];
__device__ float   g_pha[64*16384];
__device__ float   g_t1 [64*16384];
__device__ float   g_t2 [64*16384];
__device__ float   g_cat[4*48*16384];

// ---------------- matrix builders ------------------------------------------
// M05[o,m] for _frft_chirp with a=0.5 (N=128):
// phase*sqrt(c/pi)*chrp(2o-127) * sum_q chrp(q-127)*sinc((q-2m)/2)*exp(i c (2o-q)^2)
__global__ void k_build_M05() {
    int tid = blockIdx.x*blockDim.x + threadIdx.x;
    if (tid >= 128*128) return;
    int o = tid >> 7, m = tid & 127;
    const int N = 128;
    double alpha = PI_D/4.0;                 // a*pi/2, a=0.5
    double tana2 = tan(alpha*0.5);
    double sina  = sin(alpha);
    double c     = PI_D/(4.0*N*sina);
    double chc   = -PI_D/N*tana2*0.25;       // chirp coefficient (times n^2)
    double sr = 0.0, si = 0.0;
    for (int q = 0; q <= 2*N-2; ++q) {
        int d = q - 2*m;
        double s;
        if (d == 0) s = 1.0;
        else if ((d & 1) == 0) continue;     // sinc(integer) = 0
        else { double xx = 0.5*(double)d; s = sin(PI_D*xx)/(PI_D*xx); }
        int n1 = q - (N-1);
        int t  = 2*o - q;
        double ang = chc*(double)(n1*n1) + c*(double)(t*t);
        sr += s*cos(ang);
        si += s*sin(ang);
    }
    int n2 = 2*o - (N-1);
    double scale = sqrt(c/PI_D);
    double ph = -PI_D/8.0 + chc*(double)(n2*n2);  // phase * chrp(2o-127)
    double cr = cos(ph)*scale, ci = sin(ph)*scale;
    double rr = sr*cr - si*ci;
    double ii = sr*ci + si*cr;
    g_M05[tid] = make_double2(rr, ii);
    g_Mf[tid]  = make_float2((float)rr, (float)ii);
}

// Mb = M05 @ C, C[r,m] = exp(+2pi i (r+64)(m+64)/128)/sqrt(128)  (centered ifft)
__global__ void k_build_Mb() {
    int tid = blockIdx.x*blockDim.x + threadIdx.x;
    if (tid >= 128*128) return;
    int o = tid >> 7, m = tid & 127;
    double sr = 0.0, si = 0.0;
    double invs = 1.0/sqrt(128.0);
    for (int r = 0; r < 128; ++r) {
        double2 a = g_M05[(o<<7)+r];
        int k = ((r+64)*(m+64)) & 127;
        double ang = 2.0*PI_D*(double)k/128.0;
        double cr = cos(ang), ci = sin(ang);
        sr += a.x*cr - a.y*ci;
        si += a.x*ci + a.y*cr;
    }
    g_Mb[tid] = make_float2((float)(sr*invs), (float)(si*invs));
}

// F[k,n] = exp(-2pi i kn/128); IF[k,n] = exp(+2pi i kn/128)/128
__global__ void k_build_F() {
    int tid = blockIdx.x*blockDim.x + threadIdx.x;
    if (tid >= 128*128) return;
    int k = tid >> 7, n = tid & 127;
    int p = (k*n) & 127;
    double ang = 2.0*PI_D*(double)p/128.0;
    double cr = cos(ang), ci = sin(ang);
    g_F[tid]  = make_float2((float)cr, (float)(-ci));
    g_IF[tid] = make_float2((float)(cr/128.0), (float)(ci/128.0));
}

// ---------------- batched 128x128 plane transforms -------------------------
// out[p,h,j] = sum_w in[p,h,w] * A[j,w]      (X * A^T), complex
__global__ void k_rmul(const float2* __restrict__ A, const float2* __restrict__ in,
                       float2* __restrict__ out) {
    __shared__ float2 Ts[16][17];
    __shared__ float2 As[16][17];
    int p = blockIdx.z;
    int tx = threadIdx.x, ty = threadIdx.y;
    int h0 = blockIdx.y << 4, j0 = blockIdx.x << 4;
    const float2* T = in + ((long)p << 14);
    float ar = 0.f, ai = 0.f;
    for (int k0 = 0; k0 < 128; k0 += 16) {
        Ts[ty][tx] = T[((h0+ty)<<7) + k0 + tx];
        As[ty][tx] = A[((j0+ty)<<7) + k0 + tx];
        __syncthreads();
#pragma unroll
        for (int k = 0; k < 16; ++k) {
            float2 t = Ts[ty][k];
            float2 a = As[tx][k];
            ar += t.x*a.x - t.y*a.y;
            ai += t.x*a.y + t.y*a.x;
        }
        __syncthreads();
    }
    out[((long)p<<14) + ((h0+ty)<<7) + j0 + tx] = make_float2(ar, ai);
}

// out[p,h,j] = sum_w in_real[plane(p),h,w] * A[j,w]; input real planes from g_x1
__global__ void k_rmul_real(const float2* __restrict__ A, const float* __restrict__ in,
                            float2* __restrict__ out, int Ctot, int Csub, int cstart) {
    __shared__ float  Ts[16][17];
    __shared__ float2 As[16][17];
    int p = blockIdx.z;
    int n = p / Csub, c = p - n*Csub;
    int tx = threadIdx.x, ty = threadIdx.y;
    int h0 = blockIdx.y << 4, j0 = blockIdx.x << 4;
    const float* T = in + ((long)(n*Ctot + cstart + c) << 14);
    float ar = 0.f, ai = 0.f;
    for (int k0 = 0; k0 < 128; k0 += 16) {
        Ts[ty][tx] = T[((h0+ty)<<7) + k0 + tx];
        As[ty][tx] = A[((j0+ty)<<7) + k0 + tx];
        __syncthreads();
#pragma unroll
        for (int k = 0; k < 16; ++k) {
            float  t = Ts[ty][k];
            float2 a = As[tx][k];
            ar += t*a.x;
            ai += t*a.y;
        }
        __syncthreads();
    }
    out[((long)p<<14) + ((h0+ty)<<7) + j0 + tx] = make_float2(ar, ai);
}

// out[p,j,w] = sum_h A[j,h] * in[p,h,w]     (A * X), complex
__global__ void k_lmul(const float2* __restrict__ A, const float2* __restrict__ in,
                       float2* __restrict__ out) {
    __shared__ float2 As[16][17];
    __shared__ float2 Bs[16][17];
    int p = blockIdx.z;
    int tx = threadIdx.x, ty = threadIdx.y;
    int j0 = blockIdx.y << 4, w0 = blockIdx.x << 4;
    const float2* T = in + ((long)p << 14);
    float ar = 0.f, ai = 0.f;
    for (int k0 = 0; k0 < 128; k0 += 16) {
        As[ty][tx] = A[((j0+ty)<<7) + k0 + tx];
        Bs[ty][tx] = T[((k0+ty)<<7) + w0 + tx];
        __syncthreads();
#pragma unroll
        for (int k = 0; k < 16; ++k) {
            float2 a = As[ty][k];
            float2 b = Bs[k][tx];
            ar += a.x*b.x - a.y*b.y;
            ai += a.x*b.y + a.y*b.x;
        }
        __syncthreads();
    }
    out[((long)p<<14) + ((j0+ty)<<7) + w0 + tx] = make_float2(ar, ai);
}

// ---------------- tiled 1x1 conv (channel GEMM) ----------------------------
template<int CIN, int COUT>
__global__ void k_conv1x1t(const float* __restrict__ in, const float* __restrict__ w,
                           const float* __restrict__ b, float* __restrict__ out,
                           int S, int Ctot_in, int Ctot_out) {
    __shared__ float xs[4][64];
    __shared__ float ws[4][COUT];
    int n  = blockIdx.y;
    int s0 = blockIdx.x * 64;
    int t  = threadIdx.x;
    int sl = t & 63;
    int og = t >> 6;                  // 4 output groups; uniform per wave
    const int NO = COUT/4;
    float acc[NO];
#pragma unroll
    for (int j = 0; j < NO; ++j) acc[j] = 0.f;
    const float* inb = in + (long)n*Ctot_in*S + s0;
    for (int c0 = 0; c0 < CIN; c0 += 4) {
        xs[og][sl] = inb[(long)(c0+og)*S + sl];
        for (int i = t; i < 4*COUT; i += 256) {
            int cc = i / COUT, oo = i - cc*COUT;
            ws[cc][oo] = w[oo*CIN + c0 + cc];
        }
        __syncthreads();
#pragma unroll
        for (int cc = 0; cc < 4; ++cc) {
            float xv = xs[cc][sl];
#pragma unroll
            for (int j = 0; j < NO; ++j)
                acc[j] += ws[cc][og + 4*j] * xv;
        }
        __syncthreads();
    }
#pragma unroll
    for (int j = 0; j < NO; ++j) {
        int o = og + 4*j;
        float v = acc[j] + (b ? b[o] : 0.f);
        out[((long)n*Ctot_out + o)*S + s0 + sl] = v;
    }
}

// ---------------- pointwise / special kernels ------------------------------
__global__ void k_magpha(const float2* __restrict__ in, float* __restrict__ mag,
                         float* __restrict__ pha, int total) {
    int tid = blockIdx.x*blockDim.x + threadIdx.x;
    if (tid >= total) return;
    float2 v = in[tid];
    mag[tid] = sqrtf(v.x*v.x + v.y*v.y);
    pha[tid] = atan2f(v.y, v.x);
}

// region [19,109)x[19,109): t = mask1*(conv3x3(mag*mask1)+bs) + mask2*(conv1x1(mag*mask2)+bf)
__global__ void k_maskconv(const float* __restrict__ mag, const float* __restrict__ ws3,
                           const float* __restrict__ bs, const float* __restrict__ wf,
                           const float* __restrict__ bf, float* __restrict__ out) {
    int tid = blockIdx.x*blockDim.x + threadIdx.x;
    if (tid >= 4*16*16384) return;
    int w = tid & 127, h = (tid >> 7) & 127, o = (tid >> 14) & 15, n = tid >> 18;
    const float* mp = mag + (long)n*16*16384;
    bool in1 = (h >= 19 && h < 109 && w >= 19 && w < 109);
    float acc;
    if (in1) {
        acc = bs[o];
        for (int c = 0; c < 16; ++c) {
            const float* xp = mp + c*16384;
            const float* wp = ws3 + (o*16 + c)*9;
#pragma unroll
            for (int dh = -1; dh <= 1; ++dh)
#pragma unroll
                for (int dw = -1; dw <= 1; ++dw) {
                    int hh = h + dh, ww = w + dw;
                    if (hh >= 19 && hh < 109 && ww >= 19 && ww < 109)
                        acc += wp[(dh+1)*3 + (dw+1)] * xp[hh*128 + ww];
                }
        }
    } else {
        acc = bf[o];
        for (int c = 0; c < 16; ++c)
            acc += wf[o*16 + c] * mp[c*16384 + h*128 + w];
    }
    out[tid] = acc;
}

__global__ void k_combine(const float* __restrict__ m, const float* __restrict__ p,
                          float2* __restrict__ out, int total) {
    int tid = blockIdx.x*blockDim.x + threadIdx.x;
    if (tid >= total) return;
    float mm = m[tid], pp = p[tid];
    out[tid] = make_float2(mm*cosf(pp), mm*sinf(pp));
}

// read full-plane complex G at w<65 -> packed (p,128*65)
__global__ void k_magpha65(const float2* __restrict__ in, float* __restrict__ fm,
                           float* __restrict__ fp) {
    int tid = blockIdx.x*blockDim.x + threadIdx.x;
    if (tid >= 64*8320) return;
    int s = tid % 8320, pl = tid / 8320;
    int h = s / 65, w = s - h*65;
    float2 v = in[((long)pl<<14) + (h<<7) + w];
    fm[tid] = sqrtf(v.x*v.x + v.y*v.y);
    fp[tid] = atan2f(v.y, v.x);
}

// packed (mo,po) -> complex into full plane (w<65)
__global__ void k_combine65(const float* __restrict__ m, const float* __restrict__ p,
                            float2* __restrict__ out) {
    int tid = blockIdx.x*blockDim.x + threadIdx.x;
    if (tid >= 64*8320) return;
    int s = tid % 8320, pl = tid / 8320;
    int h = s / 65, w = s - h*65;
    float mm = m[tid], pp = p[tid];
    out[((long)pl<<14) + (h<<7) + w] = make_float2(mm*cosf(pp), mm*sinf(pp));
}

// Hermitian extension: S[h,w>=65] = conj(G[(128-h)%128, 128-w])
__global__ void k_extend(const float2* __restrict__ in, float2* __restrict__ out) {
    int tid = blockIdx.x*blockDim.x + threadIdx.x;
    if (tid >= 64*16384) return;
    int s = tid & 16383, pl = tid >> 14;
    int h = s >> 7, w = s & 127;
    float2 v;
    if (w < 65) v = in[tid];
    else {
        int h2 = (128 - h) & 127, w2 = 128 - w;
        float2 u = in[((long)pl<<14) + (h2<<7) + w2];
        v = make_float2(u.x, -u.y);
    }
    out[tid] = v;
}

__global__ void k_abs_to_cat(const float2* __restrict__ in, float* __restrict__ cat, int coff) {
    int tid = blockIdx.x*blockDim.x + threadIdx.x;
    if (tid >= 64*16384) return;
    int s = tid & 16383, pl = tid >> 14;
    int n = pl >> 4, c = pl & 15;
    float2 v = in[tid];
    cat[((long)(n*48 + coff + c)<<14) + s] = sqrtf(v.x*v.x + v.y*v.y);
}

__global__ void k_real_to_cat(const float2* __restrict__ in, float* __restrict__ cat, int coff) {
    int tid = blockIdx.x*blockDim.x + threadIdx.x;
    if (tid >= 64*16384) return;
    int s = tid & 16383, pl = tid >> 14;
    int n = pl >> 4, c = pl & 15;
    cat[((long)(n*48 + coff + c)<<14) + s] = in[tid].x;
}

// ---------------- launch ----------------------------------------------------
extern "C" void kernel_launch(void* const* d_in, const int* in_sizes, int n_in,
                              void* d_out, int out_size, void* d_ws, size_t ws_size,
                              hipStream_t stream) {
    (void)in_sizes; (void)n_in; (void)out_size; (void)d_ws; (void)ws_size;
    const float* x        = (const float*)d_in[0];
    const float* conv1_w  = (const float*)d_in[1];
    const float* mag_s_w  = (const float*)d_in[2];
    const float* mag_s_b  = (const float*)d_in[3];
    const float* mag_f_w  = (const float*)d_in[4];
    const float* mag_f_b  = (const float*)d_in[5];
    const float* mag_w_   = (const float*)d_in[6];
    const float* mag_b_   = (const float*)d_in[7];
    const float* pha_w_   = (const float*)d_in[8];
    const float* pha_b_   = (const float*)d_in[9];
    const float* conv_0_w = (const float*)d_in[10];
    const float* conv_0_b = (const float*)d_in[11];
    const float* conv_1_w = (const float*)d_in[12];
    const float* conv_1_b = (const float*)d_in[13];
    const float* conv2_w  = (const float*)d_in[14];
    float* outp = (float*)d_out;

    float2 *Mf, *Mb, *Fm, *IFm, *bufA, *bufB;
    float *x1, *mag, *pha, *t1, *t2, *cat;
    hipGetSymbolAddress((void**)&Mf,   HIP_SYMBOL(g_Mf));
    hipGetSymbolAddress((void**)&Mb,   HIP_SYMBOL(g_Mb));
    hipGetSymbolAddress((void**)&Fm,   HIP_SYMBOL(g_F));
    hipGetSymbolAddress((void**)&IFm,  HIP_SYMBOL(g_IF));
    hipGetSymbolAddress((void**)&bufA, HIP_SYMBOL(g_bufA));
    hipGetSymbolAddress((void**)&bufB, HIP_SYMBOL(g_bufB));
    hipGetSymbolAddress((void**)&x1,   HIP_SYMBOL(g_x1));
    hipGetSymbolAddress((void**)&mag,  HIP_SYMBOL(g_mag));
    hipGetSymbolAddress((void**)&pha,  HIP_SYMBOL(g_pha));
    hipGetSymbolAddress((void**)&t1,   HIP_SYMBOL(g_t1));
    hipGetSymbolAddress((void**)&t2,   HIP_SYMBOL(g_t2));
    hipGetSymbolAddress((void**)&cat,  HIP_SYMBOL(g_cat));

    dim3 blk2(16,16,1), grd2(8,8,64);

    // matrices (rebuilt every call — graph-safe, deterministic)
    k_build_M05<<<64, 256, 0, stream>>>();
    k_build_Mb <<<64, 256, 0, stream>>>();
    k_build_F  <<<64, 256, 0, stream>>>();

    // x1 = 1x1 conv (192 -> 48)
    k_conv1x1t<192,48><<<dim3(256,4), 256, 0, stream>>>(x, conv1_w, nullptr, x1, 16384, 192, 48);

    // FRFT forward on x_05 (channels 16..31): Fre = Mf X Mf^T
    k_rmul_real<<<grd2, blk2, 0, stream>>>(Mf, x1, bufA, 48, 16, 16);
    k_lmul     <<<grd2, blk2, 0, stream>>>(Mf, bufA, bufB);
    k_magpha   <<<4096, 256, 0, stream>>>(bufB, mag, pha, 64*16384);

    // masked conv3x3/conv1x1 + channel mixes + recombine
    k_maskconv <<<4096, 256, 0, stream>>>(mag, mag_s_w, mag_s_b, mag_f_w, mag_f_b, t1);
    k_conv1x1t<16,16><<<dim3(256,4), 256, 0, stream>>>(t1,  mag_w_, mag_b_, t2, 16384, 16, 16);
    k_conv1x1t<16,16><<<dim3(256,4), 256, 0, stream>>>(pha, pha_w_, pha_b_, t1, 16384, 16, 16);
    k_combine  <<<4096, 256, 0, stream>>>(t2, t1, bufB, 64*16384);

    // FRFT backward: |Mb Y Mb^T| -> cat channels 16..31
    k_rmul<<<grd2, blk2, 0, stream>>>(Mb, bufB, bufA);
    k_lmul<<<grd2, blk2, 0, stream>>>(Mb, bufA, bufB);
    k_abs_to_cat<<<4096, 256, 0, stream>>>(bufB, cat, 16);

    // FFT branch on x_1 (channels 32..47): G = F X F^T
    k_rmul_real<<<grd2, blk2, 0, stream>>>(Fm, x1, bufA, 48, 16, 32);
    k_lmul     <<<grd2, blk2, 0, stream>>>(Fm, bufA, bufB);
    k_magpha65 <<<2080, 256, 0, stream>>>(bufB, mag, pha);
    k_conv1x1t<16,16><<<dim3(130,4), 256, 0, stream>>>(mag, conv_1_w, conv_1_b, t1, 8320, 16, 16);
    k_conv1x1t<16,16><<<dim3(130,4), 256, 0, stream>>>(pha, conv_1_w, conv_1_b, t2, 8320, 16, 16);
    k_combine65<<<2080, 256, 0, stream>>>(t1, t2, bufA);
    k_extend   <<<4096, 256, 0, stream>>>(bufA, bufB);
    k_rmul<<<grd2, blk2, 0, stream>>>(IFm, bufB, bufA);
    k_lmul<<<grd2, blk2, 0, stream>>>(IFm, bufA, bufB);
    k_real_to_cat<<<4096, 256, 0, stream>>>(bufB, cat, 32);

    // x_0o -> cat channels 0..15
    k_conv1x1t<16,16><<<dim3(256,4), 256, 0, stream>>>(x1, conv_0_w, conv_0_b, cat, 16384, 48, 48);

    // final 1x1 conv (48 -> 192) into d_out
    k_conv1x1t<48,192><<<dim3(256,4), 256, 0, stream>>>(cat, conv2_w, nullptr, outp, 16384, 48, 192);
}

// Round 2
// 548.914 us; speedup vs baseline: 1.3918x; 1.3918x over previous
//
#include <hip/hip_runtime.h>
#include <math.h>

#define PI_D 3.14159265358979323846
#define TWO_PI_F 6.2831853071795864f

// ---------------- persistent device buffers ---------------------------------
__device__ float2  g_Mf [128*128];
__device__ float2  g_Mb [128*128];
__device__ float2  g_F  [128*128];
__device__ float2  g_IF [128*128];
__device__ float   g_x1 [4*48*16384];
__device__ float2  g_bufA[64*16384];
__device__ float2  g_bufB[64*16384];
__device__ float   g_mag[64*16384];
__device__ float   g_pha[64*16384];
__device__ float   g_t1 [64*16384];
__device__ float   g_t2 [64*16384];
__device__ float   g_cat[4*48*16384];

// ---------------- matrix builders (fp32 + fp64 angle reduction) -------------
// M05[o,m] = phase*sqrt(c/pi)*chrp(2o-127) *
//            sum_q chrp(q-127)*sinc((q-2m)/2)*exp(i c (2o-q)^2)
// sinc((q-2m)/2): q=2m -> 1; q odd -> (-1)^((d-1)/2)*2/(pi d), d=q-2m; else 0.
__global__ void k_build_M05f() {
    int tid = blockIdx.x*blockDim.x + threadIdx.x;
    if (tid >= 128*128) return;
    int o = tid >> 7, m = tid & 127;
    const double chc = -PI_D/128.0 * tan(PI_D/8.0) * 0.25;
    const double c   =  PI_D/(512.0*sin(PI_D/4.0));
    const double inv2pi = 1.0/(2.0*PI_D);
    float sr, si;
    {   // q = 2m term (sinc = 1)
        int n1 = 2*m - 127, tt = 2*(o - m);
        double ang = chc*(double)(n1*n1) + c*(double)(tt*tt);
        double r = ang*inv2pi; r -= floor(r);
        float af = (float)(r*2.0*PI_D);
        float sn, cs; __sincosf(af, &sn, &cs);
        sr = cs; si = sn;
    }
    for (int j = 0; j < 127; ++j) {
        int q  = 2*j + 1;
        int n1 = q - 127, tt = 2*o - q, d = q - 2*m;
        double ang = chc*(double)(n1*n1) + c*(double)(tt*tt);
        double r = ang*inv2pi; r -= floor(r);
        float af = (float)(r*2.0*PI_D);
        float s = (((d-1)>>1) & 1) ? -2.0f : 2.0f;
        s /= (3.14159265358979f*(float)d);
        float sn, cs; __sincosf(af, &sn, &cs);
        sr += s*cs; si += s*sn;
    }
    int n2 = 2*o - 127;
    double ph = chc*(double)(n2*n2) - PI_D/8.0;
    double r = ph*inv2pi; r -= floor(r);
    float pf = (float)(r*2.0*PI_D);
    float scale = (float)sqrt(c/PI_D);
    float sn, cs; __sincosf(pf, &sn, &cs);
    float cr = cs*scale, ci = sn*scale;
    g_Mf[tid] = make_float2(sr*cr - si*ci, sr*ci + si*cr);
}

// Mb = Mf @ C, C[r,m] = exp(+2pi i (r+64)(m+64)/128)/sqrt(128)
__global__ void k_build_Mbf() {
    __shared__ float2 W[128];
    int t = threadIdx.x;
    if (t < 128) {
        float ang = TWO_PI_F*(float)t/128.0f;
        float sn, cs; sincosf(ang, &sn, &cs);
        float invs = 0.08838834764831845f;  // 1/sqrt(128)
        W[t] = make_float2(cs*invs, sn*invs);
    }
    __syncthreads();
    int tid = blockIdx.x*blockDim.x + t;
    if (tid >= 128*128) return;
    int o = tid >> 7, m = tid & 127;
    float sr = 0.f, si = 0.f;
    for (int r = 0; r < 128; ++r) {
        float2 a = g_Mf[(o<<7) + r];
        int k = ((r+64)*(m+64)) & 127;
        float2 w = W[k];
        sr += a.x*w.x - a.y*w.y;
        si += a.x*w.y + a.y*w.x;
    }
    g_Mb[tid] = make_float2(sr, si);
}

// F[k,n] = exp(-2pi i kn/128); IF[k,n] = exp(+2pi i kn/128)/128
__global__ void k_build_Ff() {
    int tid = blockIdx.x*blockDim.x + threadIdx.x;
    if (tid >= 128*128) return;
    int k = tid >> 7, n = tid & 127;
    int p = (k*n) & 127;
    float ang = TWO_PI_F*(float)p/128.0f;
    float sn, cs; sincosf(ang, &sn, &cs);
    g_F[tid]  = make_float2(cs, -sn);
    g_IF[tid] = make_float2(cs*0.0078125f, sn*0.0078125f);
}

// ---------------- batched 128x128 plane transforms (32x32 tiles, 2x2/thread)
// out[p,h,j] = sum_w in[p,h,w] * A[j,w]   (complex x complex)
template<bool HERM>
__global__ void k_rmul32(const float2* __restrict__ A, const float2* __restrict__ in,
                         float2* __restrict__ out) {
    __shared__ float2 Ts[32][34];  // [k][h]
    __shared__ float2 As[32][34];  // [k][j]
    int p  = blockIdx.z;
    int h0 = blockIdx.y << 5, j0 = blockIdx.x << 5;
    int t  = threadIdx.x;
    int tx = t & 15, ty = t >> 4;
    int lr = t >> 5, lc = t & 31;
    const float2* T = in + ((long)p << 14);
    float2 acc[2][2] = {};
    for (int k0 = 0; k0 < 128; k0 += 32) {
#pragma unroll
        for (int i = 0; i < 4; ++i) {
            int hh = h0 + lr + 8*i;
            int ww = k0 + lc;
            float2 v;
            if (HERM && ww >= 65) {
                int h2 = (128 - hh) & 127, w2 = 128 - ww;
                float2 u = T[(h2<<7) + w2];
                v = make_float2(u.x, -u.y);
            } else {
                v = T[(hh<<7) + ww];
            }
            Ts[lc][lr + 8*i] = v;
            As[lc][lr + 8*i] = A[((j0 + lr + 8*i)<<7) + k0 + lc];
        }
        __syncthreads();
#pragma unroll
        for (int kk = 0; kk < 32; ++kk) {
            float2 a0 = Ts[kk][2*ty], a1 = Ts[kk][2*ty+1];
            float2 b0 = As[kk][2*tx], b1 = As[kk][2*tx+1];
            acc[0][0].x += a0.x*b0.x - a0.y*b0.y; acc[0][0].y += a0.x*b0.y + a0.y*b0.x;
            acc[0][1].x += a0.x*b1.x - a0.y*b1.y; acc[0][1].y += a0.x*b1.y + a0.y*b1.x;
            acc[1][0].x += a1.x*b0.x - a1.y*b0.y; acc[1][0].y += a1.x*b0.y + a1.y*b0.x;
            acc[1][1].x += a1.x*b1.x - a1.y*b1.y; acc[1][1].y += a1.x*b1.y + a1.y*b1.x;
        }
        __syncthreads();
    }
    long base = ((long)p << 14);
#pragma unroll
    for (int i = 0; i < 2; ++i)
#pragma unroll
        for (int j = 0; j < 2; ++j)
            out[base + ((h0+2*ty+i)<<7) + j0 + 2*tx + j] = acc[i][j];
}

// real input planes taken from x1 channel slice
__global__ void k_rmul_real32(const float2* __restrict__ A, const float* __restrict__ in,
                              float2* __restrict__ out, int Ctot, int Csub, int cstart) {
    __shared__ float  Ts[32][34];  // [k][h]
    __shared__ float2 As[32][34];  // [k][j]
    int p  = blockIdx.z;
    int n  = p / Csub, c = p - n*Csub;
    int h0 = blockIdx.y << 5, j0 = blockIdx.x << 5;
    int t  = threadIdx.x;
    int tx = t & 15, ty = t >> 4;
    int lr = t >> 5, lc = t & 31;
    const float* T = in + ((long)(n*Ctot + cstart + c) << 14);
    float2 acc[2][2] = {};
    for (int k0 = 0; k0 < 128; k0 += 32) {
#pragma unroll
        for (int i = 0; i < 4; ++i) {
            Ts[lc][lr + 8*i] = T[((h0 + lr + 8*i)<<7) + k0 + lc];
            As[lc][lr + 8*i] = A[((j0 + lr + 8*i)<<7) + k0 + lc];
        }
        __syncthreads();
#pragma unroll
        for (int kk = 0; kk < 32; ++kk) {
            float  a0 = Ts[kk][2*ty], a1 = Ts[kk][2*ty+1];
            float2 b0 = As[kk][2*tx], b1 = As[kk][2*tx+1];
            acc[0][0].x += a0*b0.x; acc[0][0].y += a0*b0.y;
            acc[0][1].x += a0*b1.x; acc[0][1].y += a0*b1.y;
            acc[1][0].x += a1*b0.x; acc[1][0].y += a1*b0.y;
            acc[1][1].x += a1*b1.x; acc[1][1].y += a1*b1.y;
        }
        __syncthreads();
    }
    long base = ((long)p << 14);
#pragma unroll
    for (int i = 0; i < 2; ++i)
#pragma unroll
        for (int j = 0; j < 2; ++j)
            out[base + ((h0+2*ty+i)<<7) + j0 + 2*tx + j] = acc[i][j];
}

// out[p,j,w] = sum_h A[j,h] * in[p,h,w], fused epilogues:
// EPI 0: complex->outc   1: mag/pha->o1,o2   2: abs->cat(o1)+coff
// EPI 3: real->cat(o1)+coff   4: mag/pha packed w<65 -> o1,o2
template<int EPI>
__global__ void k_lmul32(const float2* __restrict__ A, const float2* __restrict__ in,
                         float2* __restrict__ outc, float* __restrict__ o1,
                         float* __restrict__ o2, int coff) {
    __shared__ float2 As[32][34];  // [h][j] (transposed)
    __shared__ float2 Bs[32][34];  // [h][w] (natural)
    int p  = blockIdx.z;
    int j0 = blockIdx.y << 5, w0 = blockIdx.x << 5;
    int t  = threadIdx.x;
    int tx = t & 15, ty = t >> 4;
    int lr = t >> 5, lc = t & 31;
    const float2* T = in + ((long)p << 14);
    float2 acc[2][2] = {};
    for (int k0 = 0; k0 < 128; k0 += 32) {
#pragma unroll
        for (int i = 0; i < 4; ++i) {
            As[lc][lr + 8*i] = A[((j0 + lr + 8*i)<<7) + k0 + lc];
            Bs[lr + 8*i][lc] = T[((k0 + lr + 8*i)<<7) + w0 + lc];
        }
        __syncthreads();
#pragma unroll
        for (int kk = 0; kk < 32; ++kk) {
            float2 a0 = As[kk][2*ty], a1 = As[kk][2*ty+1];
            float2 b0 = Bs[kk][2*tx], b1 = Bs[kk][2*tx+1];
            acc[0][0].x += a0.x*b0.x - a0.y*b0.y; acc[0][0].y += a0.x*b0.y + a0.y*b0.x;
            acc[0][1].x += a0.x*b1.x - a0.y*b1.y; acc[0][1].y += a0.x*b1.y + a0.y*b1.x;
            acc[1][0].x += a1.x*b0.x - a1.y*b0.y; acc[1][0].y += a1.x*b0.y + a1.y*b0.x;
            acc[1][1].x += a1.x*b1.x - a1.y*b1.y; acc[1][1].y += a1.x*b1.y + a1.y*b1.x;
        }
        __syncthreads();
    }
#pragma unroll
    for (int i = 0; i < 2; ++i) {
#pragma unroll
        for (int j = 0; j < 2; ++j) {
            int jj = j0 + 2*ty + i;
            int ww = w0 + 2*tx + j;
            float2 v = acc[i][j];
            if (EPI == 0) {
                outc[((long)p<<14) + (jj<<7) + ww] = v;
            } else if (EPI == 1) {
                long idx = ((long)p<<14) + (jj<<7) + ww;
                o1[idx] = sqrtf(v.x*v.x + v.y*v.y);
                o2[idx] = atan2f(v.y, v.x);
            } else if (EPI == 2) {
                int n = p >> 4, c = p & 15;
                o1[((long)(n*48 + coff + c)<<14) + (jj<<7) + ww] = sqrtf(v.x*v.x + v.y*v.y);
            } else if (EPI == 3) {
                int n = p >> 4, c = p & 15;
                o1[((long)(n*48 + coff + c)<<14) + (jj<<7) + ww] = v.x;
            } else if (EPI == 4) {
                if (ww < 65) {
                    long idx = (long)p*8320 + jj*65 + ww;
                    o1[idx] = sqrtf(v.x*v.x + v.y*v.y);
                    o2[idx] = atan2f(v.y, v.x);
                }
            }
        }
    }
}

// ---------------- tiled 1x1 conv (channel GEMM) ----------------------------
template<int CIN, int COUT>
__global__ void k_conv1x1t(const float* __restrict__ in, const float* __restrict__ w,
                           const float* __restrict__ b, float* __restrict__ out,
                           int S, int Ctot_in, int Ctot_out) {
    __shared__ float xs[4][64];
    __shared__ float ws[4][COUT];
    int n  = blockIdx.y;
    int s0 = blockIdx.x * 64;
    int t  = threadIdx.x;
    int sl = t & 63;
    int og = t >> 6;
    const int NO = COUT/4;
    float acc[NO];
#pragma unroll
    for (int j = 0; j < NO; ++j) acc[j] = 0.f;
    const float* inb = in + (long)n*Ctot_in*S + s0;
    for (int c0 = 0; c0 < CIN; c0 += 4) {
        xs[og][sl] = inb[(long)(c0+og)*S + sl];
        for (int i = t; i < 4*COUT; i += 256) {
            int cc = i / COUT, oo = i - cc*COUT;
            ws[cc][oo] = w[oo*CIN + c0 + cc];
        }
        __syncthreads();
#pragma unroll
        for (int cc = 0; cc < 4; ++cc) {
            float xv = xs[cc][sl];
#pragma unroll
            for (int j = 0; j < NO; ++j)
                acc[j] += ws[cc][og + 4*j] * xv;
        }
        __syncthreads();
    }
#pragma unroll
    for (int j = 0; j < NO; ++j) {
        int o = og + 4*j;
        float v = acc[j] + (b ? b[o] : 0.f);
        out[((long)n*Ctot_out + o)*S + s0 + sl] = v;
    }
}

// ---------------- pointwise / special kernels ------------------------------
// region [19,109)x[19,109): mask1*(conv3x3(mag*mask1)+bs) + mask2*(conv1x1(mag*mask2)+bf)
__global__ void k_maskconv(const float* __restrict__ mag, const float* __restrict__ ws3,
                           const float* __restrict__ bs, const float* __restrict__ wf,
                           const float* __restrict__ bf, float* __restrict__ out) {
    int tid = blockIdx.x*blockDim.x + threadIdx.x;
    if (tid >= 4*16*16384) return;
    int w = tid & 127, h = (tid >> 7) & 127, o = (tid >> 14) & 15, n = tid >> 18;
    const float* mp = mag + (long)n*16*16384;
    bool in1 = (h >= 19 && h < 109 && w >= 19 && w < 109);
    float acc;
    if (in1) {
        acc = bs[o];
        for (int c = 0; c < 16; ++c) {
            const float* xp = mp + c*16384;
            const float* wp = ws3 + (o*16 + c)*9;
#pragma unroll
            for (int dh = -1; dh <= 1; ++dh)
#pragma unroll
                for (int dw = -1; dw <= 1; ++dw) {
                    int hh = h + dh, ww = w + dw;
                    if (hh >= 19 && hh < 109 && ww >= 19 && ww < 109)
                        acc += wp[(dh+1)*3 + (dw+1)] * xp[hh*128 + ww];
                }
        }
    } else {
        acc = bf[o];
        for (int c = 0; c < 16; ++c)
            acc += wf[o*16 + c] * mp[c*16384 + h*128 + w];
    }
    out[tid] = acc;
}

__global__ void k_combine(const float* __restrict__ m, const float* __restrict__ p,
                          float2* __restrict__ out, int total) {
    int tid = blockIdx.x*blockDim.x + threadIdx.x;
    if (tid >= total) return;
    float mm = m[tid], pp = p[tid];
    float sn, cs; sincosf(pp, &sn, &cs);
    out[tid] = make_float2(mm*cs, mm*sn);
}

// packed (mo,po) -> complex into full plane (w<65)
__global__ void k_combine65(const float* __restrict__ m, const float* __restrict__ p,
                            float2* __restrict__ out) {
    int tid = blockIdx.x*blockDim.x + threadIdx.x;
    if (tid >= 64*8320) return;
    int s = tid % 8320, pl = tid / 8320;
    int h = s / 65, w = s - h*65;
    float mm = m[tid], pp = p[tid];
    float sn, cs; sincosf(pp, &sn, &cs);
    out[((long)pl<<14) + (h<<7) + w] = make_float2(mm*cs, mm*sn);
}

// ---------------- launch ----------------------------------------------------
extern "C" void kernel_launch(void* const* d_in, const int* in_sizes, int n_in,
                              void* d_out, int out_size, void* d_ws, size_t ws_size,
                              hipStream_t stream) {
    (void)in_sizes; (void)n_in; (void)out_size; (void)d_ws; (void)ws_size;
    const float* x        = (const float*)d_in[0];
    const float* conv1_w  = (const float*)d_in[1];
    const float* mag_s_w  = (const float*)d_in[2];
    const float* mag_s_b  = (const float*)d_in[3];
    const float* mag_f_w  = (const float*)d_in[4];
    const float* mag_f_b  = (const float*)d_in[5];
    const float* mag_w_   = (const float*)d_in[6];
    const float* mag_b_   = (const float*)d_in[7];
    const float* pha_w_   = (const float*)d_in[8];
    const float* pha_b_   = (const float*)d_in[9];
    const float* conv_0_w = (const float*)d_in[10];
    const float* conv_0_b = (const float*)d_in[11];
    const float* conv_1_w = (const float*)d_in[12];
    const float* conv_1_b = (const float*)d_in[13];
    const float* conv2_w  = (const float*)d_in[14];
    float* outp = (float*)d_out;

    float2 *Mf, *Mb, *Fm, *IFm, *bufA, *bufB;
    float *x1, *mag, *pha, *t1, *t2, *cat;
    hipGetSymbolAddress((void**)&Mf,   HIP_SYMBOL(g_Mf));
    hipGetSymbolAddress((void**)&Mb,   HIP_SYMBOL(g_Mb));
    hipGetSymbolAddress((void**)&Fm,   HIP_SYMBOL(g_F));
    hipGetSymbolAddress((void**)&IFm,  HIP_SYMBOL(g_IF));
    hipGetSymbolAddress((void**)&bufA, HIP_SYMBOL(g_bufA));
    hipGetSymbolAddress((void**)&bufB, HIP_SYMBOL(g_bufB));
    hipGetSymbolAddress((void**)&x1,   HIP_SYMBOL(g_x1));
    hipGetSymbolAddress((void**)&mag,  HIP_SYMBOL(g_mag));
    hipGetSymbolAddress((void**)&pha,  HIP_SYMBOL(g_pha));
    hipGetSymbolAddress((void**)&t1,   HIP_SYMBOL(g_t1));
    hipGetSymbolAddress((void**)&t2,   HIP_SYMBOL(g_t2));
    hipGetSymbolAddress((void**)&cat,  HIP_SYMBOL(g_cat));

    dim3 blk(256,1,1), grd(4,4,64);

    // matrices (rebuilt every call — graph-safe, deterministic)
    k_build_M05f<<<64, 256, 0, stream>>>();
    k_build_Mbf <<<64, 256, 0, stream>>>();
    k_build_Ff  <<<64, 256, 0, stream>>>();

    // x1 = 1x1 conv (192 -> 48)
    k_conv1x1t<192,48><<<dim3(256,4), 256, 0, stream>>>(x, conv1_w, nullptr, x1, 16384, 192, 48);

    // FRFT forward on x_05 (channels 16..31): Fre = Mf X Mf^T; fused mag/pha
    k_rmul_real32<<<grd, blk, 0, stream>>>(Mf, x1, bufA, 48, 16, 16);
    k_lmul32<1>  <<<grd, blk, 0, stream>>>(Mf, bufA, nullptr, mag, pha, 0);

    // masked conv3x3/conv1x1 + channel mixes + recombine
    k_maskconv <<<4096, 256, 0, stream>>>(mag, mag_s_w, mag_s_b, mag_f_w, mag_f_b, t1);
    k_conv1x1t<16,16><<<dim3(256,4), 256, 0, stream>>>(t1,  mag_w_, mag_b_, t2, 16384, 16, 16);
    k_conv1x1t<16,16><<<dim3(256,4), 256, 0, stream>>>(pha, pha_w_, pha_b_, t1, 16384, 16, 16);
    k_combine  <<<4096, 256, 0, stream>>>(t2, t1, bufB, 64*16384);

    // FRFT backward: |Mb Y Mb^T| -> cat channels 16..31 (fused abs)
    k_rmul32<false><<<grd, blk, 0, stream>>>(Mb, bufB, bufA);
    k_lmul32<2>    <<<grd, blk, 0, stream>>>(Mb, bufA, nullptr, cat, nullptr, 16);

    // FFT branch on x_1 (channels 32..47): G = F X F^T; fused packed mag/pha
    k_rmul_real32<<<grd, blk, 0, stream>>>(Fm, x1, bufA, 48, 16, 32);
    k_lmul32<4>  <<<grd, blk, 0, stream>>>(Fm, bufA, nullptr, mag, pha, 0);
    k_conv1x1t<16,16><<<dim3(130,4), 256, 0, stream>>>(mag, conv_1_w, conv_1_b, t1, 8320, 16, 16);
    k_conv1x1t<16,16><<<dim3(130,4), 256, 0, stream>>>(pha, conv_1_w, conv_1_b, t2, 8320, 16, 16);
    k_combine65<<<2080, 256, 0, stream>>>(t1, t2, bufA);
    // inverse rfft2: Hermitian extension fused into the loader
    k_rmul32<true><<<grd, blk, 0, stream>>>(IFm, bufA, bufB);
    k_lmul32<3>   <<<grd, blk, 0, stream>>>(IFm, bufB, nullptr, cat, nullptr, 32);

    // x_0o -> cat channels 0..15
    k_conv1x1t<16,16><<<dim3(256,4), 256, 0, stream>>>(x1, conv_0_w, conv_0_b, cat, 16384, 48, 48);

    // final 1x1 conv (48 -> 192) into d_out
    k_conv1x1t<48,192><<<dim3(256,4), 256, 0, stream>>>(cat, conv2_w, nullptr, outp, 16384, 48, 192);
}